// Round 9
// baseline (123.164 us; speedup 1.0000x reference)
//
#include <hip/hip_runtime.h>
#include <hip/hip_bf16.h>

// Problem constants (fixed by reference setup_inputs)
constexpr int B_ = 4, C_ = 512, N_ = 4096, NH_ = 8, HD_ = 64;
constexpr int NK = 1024;            // (64/2)*(64/2)
constexpr float SCALE = 0.125f;     // HD^-0.5
constexpr float EPS = 1e-5f;

typedef __attribute__((ext_vector_type(8))) short bf16x8;
typedef __attribute__((ext_vector_type(4))) float f32x4;

__device__ __forceinline__ short bf16s(float f) {
    __hip_bfloat16 h = __float2bfloat16(f);
    return *reinterpret_cast<short*>(&h);
}
__device__ __forceinline__ float bf2f(short s) {
    return __bfloat162float(*reinterpret_cast<__hip_bfloat16*>(&s));
}

#define GLD16(gp, lp)                                                                     \
    __builtin_amdgcn_global_load_lds((const __attribute__((address_space(1))) void*)(gp), \
                                     (__attribute__((address_space(3))) void*)(lp), 16, 0, 0)

// ---------------------------------------------------------------------------
// P1 merged: xprep (2048 blocks) | wprep (512) | wsrT (256)
__global__ __launch_bounds__(256) void k_xw(const float* __restrict__ x,
                                            const float* __restrict__ Wq, const float* __restrict__ Wk,
                                            const float* __restrict__ gamma, const float* __restrict__ beta,
                                            const float* __restrict__ mean, const float* __restrict__ var,
                                            const float* __restrict__ bsr, const float* __restrict__ Wsr,
                                            short* __restrict__ xT, float* __restrict__ vpart,
                                            short* __restrict__ Wq16, short* __restrict__ Wkp16,
                                            float* __restrict__ bk, short* __restrict__ WsrT) {
    const int bid = blockIdx.x, tid = threadIdx.x;
    __shared__ float t[64][65];
    if (bid < 2048) {
        const int y = bid & 63, ct = (bid >> 6) & 7, b = bid >> 9;
        {
            const int cc = tid >> 2, q = tid & 3;
            const float* xr = x + ((size_t)(b * C_ + ct * 64 + cc)) * N_ + y * 64;
            float s = 0.f;
#pragma unroll
            for (int jj = 0; jj < 4; ++jj) {
                float4 f = *reinterpret_cast<const float4*>(&xr[q * 16 + jj * 4]);
                int n = q * 16 + jj * 4;
                t[n + 0][cc] = f.x; t[n + 1][cc] = f.y;
                t[n + 2][cc] = f.z; t[n + 3][cc] = f.w;
                s += f.x + f.y + f.z + f.w;
            }
            s += __shfl_xor(s, 1);
            s += __shfl_xor(s, 2);
            if (q == 0) vpart[((size_t)(y * B_ + b)) * C_ + ct * 64 + cc] = s;
        }
        __syncthreads();
        {
            const int n = tid >> 2, c0 = (tid & 3) * 16;
            bf16x8 u0, u1;
#pragma unroll
            for (int j = 0; j < 8; ++j) {
                u0[j] = bf16s(t[n][c0 + j]);
                u1[j] = bf16s(t[n][c0 + 8 + j]);
            }
            short* dst = xT + ((size_t)(b * N_ + y * 64 + n)) * C_ + ct * 64 + c0;
            *reinterpret_cast<bf16x8*>(dst) = u0;
            *reinterpret_cast<bf16x8*>(dst + 8) = u1;
        }
    } else if (bid < 2560) {
        const int o = bid - 2048;
        float acc = 0.f;
        for (int c = tid; c < C_; c += 256) {
            float sc = rsqrtf(var[c] + EPS) * gamma[c];
            float wk = Wk[o * C_ + c];
            Wkp16[o * C_ + c] = bf16s(wk * sc);
            Wq16[o * C_ + c] = bf16s(Wq[o * C_ + c]);
            acc += wk * (sc * (bsr[c] - mean[c]) + beta[c]);
        }
        for (int m = 32; m; m >>= 1) acc += __shfl_xor(acc, m);
        if ((tid & 63) == 0) t[0][tid >> 6] = acc;
        __syncthreads();
        if (tid == 0) bk[o] = t[0][0] + t[0][1] + t[0][2] + t[0][3];
    } else {
        const int r = bid - 2560, kt = r & 31, ot = r >> 5;
        {
            const int cc = tid >> 2, q = tid & 3;
            const float* xr = Wsr + (size_t)(ot * 64 + cc) * 2048 + kt * 64;
#pragma unroll
            for (int jj = 0; jj < 4; ++jj) {
                float4 f = *reinterpret_cast<const float4*>(&xr[q * 16 + jj * 4]);
                int n = q * 16 + jj * 4;
                t[n + 0][cc] = f.x; t[n + 1][cc] = f.y;
                t[n + 2][cc] = f.z; t[n + 3][cc] = f.w;
            }
        }
        __syncthreads();
        {
            const int n = tid >> 2, c0 = (tid & 3) * 16;
            bf16x8 u0, u1;
#pragma unroll
            for (int j = 0; j < 8; ++j) {
                u0[j] = bf16s(t[n][c0 + j]);
                u1[j] = bf16s(t[n][c0 + 8 + j]);
            }
            int gkk = kt * 64 + n;                      // ci-major index
            int row2 = (gkk & 3) * 512 + (gkk >> 2);    // (dy,dx)-major index kk'
            short* dst = WsrT + (size_t)row2 * C_ + ot * 64 + c0;
            *reinterpret_cast<bf16x8*>(dst) = u0;
            *reinterpret_cast<bf16x8*>(dst + 8) = u1;
        }
    }
}

// ---------------------------------------------------------------------------
// m97-style GEMM core (128xBN tiles): acc += A[rows][K] * B[rows][K]^T
template <int MT>
__device__ __forceinline__ void gemm_core(const short* __restrict__ Ag,
                                          const short* __restrict__ Bg, int K,
                                          short* Abuf, short* Bbuf,
                                          f32x4 (&acc)[MT][4]) {
    const int tid = threadIdx.x;
    const int w = tid >> 6, l = tid & 63;
    const int lr = l & 15, lg = l >> 4;
    const int wm = w >> 1, wn = w & 1;
    const int srow = tid >> 3, scol = (tid & 7) * 8;
    char* AbufC = (char*)Abuf;
    char* BbufC = (char*)Bbuf;
    for (int kt = 0; kt < K; kt += 64) {
#pragma unroll
        for (int i = 0; i < MT; ++i)
            GLD16(Ag + (size_t)(i * 32 + srow) * K + kt + scol, AbufC + i * 4096 + tid * 16);
#pragma unroll
        for (int i = 0; i < 4; ++i)
            GLD16(Bg + (size_t)(i * 32 + srow) * K + kt + scol, BbufC + i * 4096 + tid * 16);
        __syncthreads();
        bf16x8 af[MT][2], bfv[4][2];
#pragma unroll
        for (int mt = 0; mt < MT; ++mt)
#pragma unroll
            for (int ks = 0; ks < 2; ++ks)
                af[mt][ks] = *reinterpret_cast<const bf16x8*>(
                    &Abuf[(wm * MT * 16 + mt * 16 + lr) * 64 + ks * 32 + lg * 8]);
#pragma unroll
        for (int nt = 0; nt < 4; ++nt)
#pragma unroll
            for (int ks = 0; ks < 2; ++ks)
                bfv[nt][ks] = *reinterpret_cast<const bf16x8*>(
                    &Bbuf[(wn * 64 + nt * 16 + lr) * 64 + ks * 32 + lg * 8]);
#pragma unroll
        for (int mt = 0; mt < MT; ++mt)
#pragma unroll
            for (int nt = 0; nt < 4; ++nt) {
                acc[mt][nt] = __builtin_amdgcn_mfma_f32_16x16x32_bf16(af[mt][0], bfv[nt][0], acc[mt][nt], 0, 0, 0);
                acc[mt][nt] = __builtin_amdgcn_mfma_f32_16x16x32_bf16(af[mt][1], bfv[nt][1], acc[mt][nt], 0, 0, 0);
            }
        __syncthreads();
    }
}

// ---------------------------------------------------------------------------
// P2 merged: Wck 64x64-tile GEMM (256 blocks) | pvred (32 blocks)
__global__ __launch_bounds__(256) void k_wckpv(const short* __restrict__ WsrT,
                                               const short* __restrict__ Wkp16,
                                               const float* __restrict__ vpart,
                                               const float* __restrict__ Wproj,
                                               short* __restrict__ Wck16,
                                               float* __restrict__ pv) {
    const int bid = blockIdx.x, tid = threadIdx.x;
    if (bid < 256) {
        __shared__ short Ab[64 * 64];
        __shared__ short Bb[64 * 64];
        const int m0 = (bid & 31) * 64;   // kk'
        const int n0 = (bid >> 5) * 64;   // o
        const int w = tid >> 6, l = tid & 63;
        const int lr = l & 15, lg = l >> 4, wm = w >> 1, wn = w & 1;
        const int srow = tid >> 3, scol = (tid & 7) * 8;  // shorts
        f32x4 acc[2][2];
#pragma unroll
        for (int i = 0; i < 2; ++i)
#pragma unroll
            for (int j = 0; j < 2; ++j) acc[i][j] = (f32x4){0.f, 0.f, 0.f, 0.f};
        char* AbC = (char*)Ab;
        char* BbC = (char*)Bb;
        for (int kt = 0; kt < 512; kt += 64) {
#pragma unroll
            for (int j = 0; j < 2; ++j) {
                GLD16(WsrT + (size_t)(m0 + j * 32 + srow) * 512 + kt + scol, AbC + j * 4096 + tid * 16);
                GLD16(Wkp16 + (size_t)(n0 + j * 32 + srow) * 512 + kt + scol, BbC + j * 4096 + tid * 16);
            }
            __syncthreads();
            bf16x8 af[2][2], bfv[2][2];
#pragma unroll
            for (int mt = 0; mt < 2; ++mt)
#pragma unroll
                for (int ks = 0; ks < 2; ++ks)
                    af[mt][ks] = *reinterpret_cast<const bf16x8*>(
                        &Ab[(wm * 32 + mt * 16 + lr) * 64 + ks * 32 + lg * 8]);
#pragma unroll
            for (int nt = 0; nt < 2; ++nt)
#pragma unroll
                for (int ks = 0; ks < 2; ++ks)
                    bfv[nt][ks] = *reinterpret_cast<const bf16x8*>(
                        &Bb[(wn * 32 + nt * 16 + lr) * 64 + ks * 32 + lg * 8]);
#pragma unroll
            for (int mt = 0; mt < 2; ++mt)
#pragma unroll
                for (int nt = 0; nt < 2; ++nt) {
                    acc[mt][nt] = __builtin_amdgcn_mfma_f32_16x16x32_bf16(af[mt][0], bfv[nt][0], acc[mt][nt], 0, 0, 0);
                    acc[mt][nt] = __builtin_amdgcn_mfma_f32_16x16x32_bf16(af[mt][1], bfv[nt][1], acc[mt][nt], 0, 0, 0);
                }
            __syncthreads();
        }
#pragma unroll
        for (int mt = 0; mt < 2; ++mt)
#pragma unroll
            for (int nt = 0; nt < 2; ++nt) {
                int kk0 = m0 + wm * 32 + mt * 16 + lg * 4;
                int o = n0 + wn * 32 + nt * 16 + lr;
                short4 u;
                u.x = bf16s(acc[mt][nt][0]);
                u.y = bf16s(acc[mt][nt][1]);
                u.z = bf16s(acc[mt][nt][2]);
                u.w = bf16s(acc[mt][nt][3]);
                *reinterpret_cast<short4*>(&Wck16[(size_t)o * 2048 + kk0]) = u;
            }
    } else {
        const int r = bid - 256, oc = r & 7, b = r >> 3;
        __shared__ float vs[512];
        float2 s = {0.f, 0.f};
        for (int y = 0; y < 64; ++y) {
            float2 f = *reinterpret_cast<const float2*>(&vpart[((size_t)(y * B_ + b)) * C_ + tid * 2]);
            s.x += f.x; s.y += f.y;
        }
        vs[tid * 2] = s.x * (1.f / N_);
        vs[tid * 2 + 1] = s.y * (1.f / N_);
        __syncthreads();
        const int w = tid >> 6, l = tid & 63;
#pragma unroll 4
        for (int i = 0; i < 16; ++i) {
            int o = oc * 64 + i * 4 + w;
            const float* wr = Wproj + (size_t)o * C_;
            float4 a = *reinterpret_cast<const float4*>(&wr[l * 8]);
            float4 b4 = *reinterpret_cast<const float4*>(&wr[l * 8 + 4]);
            float acc = a.x * vs[l * 8] + a.y * vs[l * 8 + 1] + a.z * vs[l * 8 + 2] + a.w * vs[l * 8 + 3] +
                        b4.x * vs[l * 8 + 4] + b4.y * vs[l * 8 + 5] + b4.z * vs[l * 8 + 6] + b4.w * vs[l * 8 + 7];
            for (int m = 32; m; m >>= 1) acc += __shfl_xor(acc, m);
            if (l == 0) pv[b * C_ + o] = acc;
        }
    }
}

// ---------------------------------------------------------------------------
// Fused q-GEMM + split-K(x4) k-GEMM. 1024 blocks, uniform K=512, XCD-swizzled.
__global__ __launch_bounds__(256) void k_gemm_qk2(const short* __restrict__ xT,
                                                  const short* __restrict__ Wq16,
                                                  const short* __restrict__ Wck16,
                                                  short* __restrict__ kp,
                                                  short* __restrict__ q2) {
    __shared__ short Abuf[128 * 64];
    __shared__ short Bbuf[128 * 64];
    f32x4 acc[4][4];
#pragma unroll
    for (int i = 0; i < 4; ++i)
#pragma unroll
        for (int j = 0; j < 4; ++j) acc[i][j] = (f32x4){0.f, 0.f, 0.f, 0.f};
    // XCD-aware swizzle (nwg=1024, 8 XCDs): each XCD gets a contiguous logical chunk
    const int bid = (blockIdx.x & 7) * 128 + (blockIdx.x >> 3);
    const int tid = threadIdx.x, l = tid & 63, w = tid >> 6;
    const int lr = l & 15, lg = l >> 4, wm = w >> 1, wn = w & 1;
    const int srow = tid >> 3, scol = (tid & 7) * 8;
    char* AbufC = (char*)Abuf;
    char* BbufC = (char*)Bbuf;

    if (bid < 512) {
        const int s = bid >> 7;            // dy*2 + dx
        const int dy = s >> 1, dx = s & 1;
        const int r2 = bid & 127;
        const int n0 = (r2 >> 2) * 128;    // act tile (bp)
        const int m0 = (r2 & 3) * 128;     // weight tile (o)
        for (int kt2 = 0; kt2 < 512; kt2 += 64) {
#pragma unroll
            for (int i = 0; i < 4; ++i) {
                int bp = n0 + i * 32 + srow;
                int b = bp >> 10, p = bp & 1023;
                int n = ((p >> 5) * 2 + dy) * 64 + (p & 31) * 2 + dx;
                GLD16(xT + ((size_t)(b * N_ + n)) * C_ + kt2 + scol, AbufC + i * 4096 + tid * 16);
            }
#pragma unroll
            for (int i = 0; i < 4; ++i)
                GLD16(Wck16 + (size_t)(m0 + i * 32 + srow) * 2048 + s * 512 + kt2 + scol,
                      BbufC + i * 4096 + tid * 16);
            __syncthreads();
            bf16x8 af[4][2], bfv[4][2];
#pragma unroll
            for (int mt = 0; mt < 4; ++mt)
#pragma unroll
                for (int ks = 0; ks < 2; ++ks)
                    af[mt][ks] = *reinterpret_cast<const bf16x8*>(
                        &Abuf[(wm * 64 + mt * 16 + lr) * 64 + ks * 32 + lg * 8]);
#pragma unroll
            for (int nt = 0; nt < 4; ++nt)
#pragma unroll
                for (int ks = 0; ks < 2; ++ks)
                    bfv[nt][ks] = *reinterpret_cast<const bf16x8*>(
                        &Bbuf[(wn * 64 + nt * 16 + lr) * 64 + ks * 32 + lg * 8]);
#pragma unroll
            for (int mt = 0; mt < 4; ++mt)
#pragma unroll
                for (int nt = 0; nt < 4; ++nt) {
                    acc[mt][nt] = __builtin_amdgcn_mfma_f32_16x16x32_bf16(af[mt][0], bfv[nt][0], acc[mt][nt], 0, 0, 0);
                    acc[mt][nt] = __builtin_amdgcn_mfma_f32_16x16x32_bf16(af[mt][1], bfv[nt][1], acc[mt][nt], 0, 0, 0);
                }
            __syncthreads();
        }
        short* kps = kp + (size_t)s * (4096 * 512);
#pragma unroll
        for (int mt = 0; mt < 4; ++mt)
#pragma unroll
            for (int nt = 0; nt < 4; ++nt) {
                int o = m0 + wn * 64 + nt * 16 + lr;
#pragma unroll
                for (int r = 0; r < 4; ++r) {
                    int bp = n0 + wm * 64 + mt * 16 + lg * 4 + r;
                    kps[(size_t)bp * 512 + o] = bf16s(acc[mt][nt][r]);
                }
            }
    } else {
        const int bq = bid - 512;
        const int m0 = (bq & 3) * 128, n0 = (bq >> 2) * 128;
        gemm_core<4>(Wq16 + (size_t)m0 * 512, xT + (size_t)n0 * 512, 512, Abuf, Bbuf, acc);
#pragma unroll
        for (int mt = 0; mt < 4; ++mt) {
            const int o0 = m0 + wm * 64 + mt * 16 + lg * 4;
            const int h = o0 >> 6, d0 = o0 & 63;
#pragma unroll
            for (int nt = 0; nt < 4; ++nt) {
                int ng = n0 + wn * 64 + nt * 16 + lr;
                int b = ng >> 12, n = ng & 4095;
                short4 u;
                u.x = bf16s(acc[mt][nt][0]);
                u.y = bf16s(acc[mt][nt][1]);
                u.z = bf16s(acc[mt][nt][2]);
                u.w = bf16s(acc[mt][nt][3]);
                *reinterpret_cast<short4*>(&q2[(((size_t)(b * NH_ + h)) * N_ + n) * HD_ + d0]) = u;
            }
        }
    }
}

// ---------------------------------------------------------------------------
// kred, 16B-vectorized: k3[b,h,p,d] = bf16( sum_s kp[s][bp][o] + bk[o] )
// grid 1024 x 256: each block 4 bp rows, each lane 8 o's.
__global__ __launch_bounds__(256) void k_kred(const short* __restrict__ kp,
                                              const float* __restrict__ bk,
                                              short* __restrict__ k3) {
    const int r = blockIdx.x * 4 + (threadIdx.x >> 6);   // bp row
    const int o0 = (threadIdx.x & 63) * 8;
    const int b = r >> 10, p = r & 1023;
    const short* base = kp + (size_t)r * 512 + o0;
    float s[8];
    float4 b0 = *reinterpret_cast<const float4*>(&bk[o0]);
    float4 b1 = *reinterpret_cast<const float4*>(&bk[o0 + 4]);
    s[0] = b0.x; s[1] = b0.y; s[2] = b0.z; s[3] = b0.w;
    s[4] = b1.x; s[5] = b1.y; s[6] = b1.z; s[7] = b1.w;
#pragma unroll
    for (int sp = 0; sp < 4; ++sp) {
        bf16x8 v = *reinterpret_cast<const bf16x8*>(base + (size_t)sp * (4096 * 512));
#pragma unroll
        for (int j = 0; j < 8; ++j) s[j] += bf2f(v[j]);
    }
    bf16x8 u;
#pragma unroll
    for (int j = 0; j < 8; ++j) u[j] = bf16s(s[j]);
    const int h = o0 >> 6, d = o0 & 63;
    *reinterpret_cast<bf16x8*>(&k3[(((size_t)(b * NH_ + h)) * NK + p) * HD_ + d]) = u;
}

// ---------------------------------------------------------------------------
// Fused attention + epilogue. Grid (64 n-tiles, B_), 512 thr = 8 waves.
// Per block: loop h=0..7: waves split 1024 p (128 each); max over p for 64 n;
// cross-wave LDS max; ssum[n] += SCALE*max. Then out[b,:,n-tile] = pv (x) ssum + bproj.
__global__ __launch_bounds__(512) void k_attnf(const short* __restrict__ k3,
                                               const short* __restrict__ q2,
                                               const float* __restrict__ pv,
                                               const float* __restrict__ bproj,
                                               float* __restrict__ out) {
    const int b = blockIdx.y, n0 = blockIdx.x * 64;
    const int tid = threadIdx.x, w = tid >> 6, l = tid & 63;
    const int lr = l & 15, lg = l >> 4;
    __shared__ float sm[8][64];
    __shared__ float ssum[64];
    if (tid < 64) ssum[tid] = 0.f;

    for (int h = 0; h < NH_; ++h) {
        const short* qb = q2 + ((size_t)(b * NH_ + h)) * N_ * HD_;
        const short* kb = k3 + ((size_t)(b * NH_ + h)) * NK * HD_ + (size_t)(w * 128) * HD_;
        bf16x8 bq[4][2];
#pragma unroll
        for (int nt = 0; nt < 4; ++nt)
#pragma unroll
            for (int ks = 0; ks < 2; ++ks)
                bq[nt][ks] = *reinterpret_cast<const bf16x8*>(
                    &qb[(size_t)(n0 + nt * 16 + lr) * HD_ + ks * 32 + lg * 8]);
        float rmax[4];
#pragma unroll
        for (int nt = 0; nt < 4; ++nt) rmax[nt] = -3.4e38f;

        const short* s0p = kb + (size_t)lr * HD_ + lg * 8;
        bf16x8 a0 = *reinterpret_cast<const bf16x8*>(s0p);
        bf16x8 a1 = *reinterpret_cast<const bf16x8*>(s0p + 32);
        for (int t = 0; t < 8; ++t) {
            bf16x8 c0 = a0, c1 = a1;
            if (t < 7) {
                const short* s2 = kb + (size_t)((t + 1) * 16 + lr) * HD_ + lg * 8;
                a0 = *reinterpret_cast<const bf16x8*>(s2);
                a1 = *reinterpret_cast<const bf16x8*>(s2 + 32);
            }
            __builtin_amdgcn_s_setprio(1);
#pragma unroll
            for (int nt = 0; nt < 4; ++nt) {
                f32x4 acc = {0.f, 0.f, 0.f, 0.f};
                acc = __builtin_amdgcn_mfma_f32_16x16x32_bf16(c0, bq[nt][0], acc, 0, 0, 0);
                acc = __builtin_amdgcn_mfma_f32_16x16x32_bf16(c1, bq[nt][1], acc, 0, 0, 0);
                rmax[nt] = fmaxf(fmaxf(fmaxf(fmaxf(acc[0], acc[1]), acc[2]), acc[3]), rmax[nt]);
            }
            __builtin_amdgcn_s_setprio(0);
        }
#pragma unroll
        for (int nt = 0; nt < 4; ++nt) {
            float m = rmax[nt];
            m = fmaxf(m, __shfl_xor(m, 16));
            m = fmaxf(m, __shfl_xor(m, 32));
            rmax[nt] = m;
        }
        if (lg == 0) {
#pragma unroll
            for (int nt = 0; nt < 4; ++nt) sm[w][nt * 16 + lr] = rmax[nt];
        }
        __syncthreads();
        if (tid < 64) {
            float m = sm[0][tid];
#pragma unroll
            for (int ww = 1; ww < 8; ++ww) m = fmaxf(m, sm[ww][tid]);
            ssum[tid] += SCALE * m;
        }
        __syncthreads();
    }
    // epilogue: out[b, o, n0..n0+63] = pv[b,o] * ssum + bproj[o]
    const float* pvb = pv + b * C_;
    float* ob = out + (size_t)b * C_ * N_ + n0;
    float4 sv = *reinterpret_cast<const float4*>(&ssum[(tid & 15) * 4]);
#pragma unroll 4
    for (int pass = 0; pass < 16; ++pass) {
        int o = pass * 32 + (tid >> 4);
        float p = pvb[o], bp = bproj[o];
        float4 rr = {p * sv.x + bp, p * sv.y + bp, p * sv.z + bp, p * sv.w + bp};
        *reinterpret_cast<float4*>(&ob[(size_t)o * N_ + (tid & 15) * 4]) = rr;
    }
}

// ---------------------------------------------------------------------------
extern "C" void kernel_launch(void* const* d_in, const int* in_sizes, int n_in,
                              void* d_out, int out_size, void* d_ws, size_t ws_size,
                              hipStream_t stream) {
    const float* x     = (const float*)d_in[0];
    const float* Wq    = (const float*)d_in[2];
    const float* Wk    = (const float*)d_in[3];
    const float* Wsr   = (const float*)d_in[4];
    const float* bsr   = (const float*)d_in[5];
    const float* gamma = (const float*)d_in[6];
    const float* beta  = (const float*)d_in[7];
    const float* mean  = (const float*)d_in[8];
    const float* var   = (const float*)d_in[9];
    const float* Wproj = (const float*)d_in[10];
    const float* bproj = (const float*)d_in[11];
    float* out = (float*)d_out;

    char* ws = (char*)d_ws;
    float* vpart = (float*)(ws + 0);         // 512 KB [64][B][C]
    float* pv    = (float*)(ws + 524288);    // 8 KB
    float* bk    = (float*)(ws + 532480);    // 4 KB
    short* Wq16  = (short*)(ws + 1060864);   // 512 KB
    short* Wkp16 = (short*)(ws + 1585152);   // 512 KB
    short* WsrT  = (short*)(ws + 2109440);   // 2 MB   [kk'][co] bf16
    short* Wck16 = (short*)(ws + 4206592);   // 2 MB   [o][kk'] bf16
    short* xT    = (short*)(ws + 6303744);   // 16 MB  [b,n,c] bf16
    short* q2    = (short*)(ws + 23080960);  // 16 MB  [b,h,n,d] bf16
    short* k3    = (short*)(ws + 39858176);  // 4 MB   [b,h,p,d] bf16
    short* kp    = (short*)(ws + 44052480);  // 16 MB  [4][4096][512] bf16

    k_xw<<<dim3(2816), 256, 0, stream>>>(x, Wq, Wk, gamma, beta, mean, var, bsr, Wsr,
                                         xT, vpart, Wq16, Wkp16, bk, WsrT);
    k_wckpv<<<dim3(288), 256, 0, stream>>>(WsrT, Wkp16, vpart, Wproj, Wck16, pv);
    k_gemm_qk2<<<dim3(1024), 256, 0, stream>>>(xT, Wq16, Wck16, kp, q2);
    k_kred<<<dim3(1024), 256, 0, stream>>>(kp, bk, k3);
    k_attnf<<<dim3(64, B_), 512, 0, stream>>>(k3, q2, pv, bproj, out);
}

// Round 10
// 92.054 us; speedup vs baseline: 1.3380x; 1.3380x over previous
//
#include <hip/hip_runtime.h>
#include <hip/hip_bf16.h>

// Problem constants (fixed by reference setup_inputs)
constexpr int B_ = 4, C_ = 512, N_ = 4096, NH_ = 8, HD_ = 64;
constexpr int NK = 1024;            // (64/2)*(64/2)
constexpr float SCALE = 0.125f;     // HD^-0.5
constexpr float EPS = 1e-5f;

typedef __attribute__((ext_vector_type(8))) short bf16x8;
typedef __attribute__((ext_vector_type(4))) float f32x4;

__device__ __forceinline__ short bf16s(float f) {
    __hip_bfloat16 h = __float2bfloat16(f);
    return *reinterpret_cast<short*>(&h);
}
__device__ __forceinline__ float bf2f(short s) {
    return __bfloat162float(*reinterpret_cast<__hip_bfloat16*>(&s));
}

#define GLD16(gp, lp)                                                                     \
    __builtin_amdgcn_global_load_lds((const __attribute__((address_space(1))) void*)(gp), \
                                     (__attribute__((address_space(3))) void*)(lp), 16, 0, 0)

// ---------------------------------------------------------------------------
// P1 merged: xprep (2048 blocks) | wprep (512) | wsrT (256)
__global__ __launch_bounds__(256) void k_xw(const float* __restrict__ x,
                                            const float* __restrict__ Wq, const float* __restrict__ Wk,
                                            const float* __restrict__ gamma, const float* __restrict__ beta,
                                            const float* __restrict__ mean, const float* __restrict__ var,
                                            const float* __restrict__ bsr, const float* __restrict__ Wsr,
                                            short* __restrict__ xT, float* __restrict__ vpart,
                                            short* __restrict__ Wq16, short* __restrict__ Wkp16,
                                            float* __restrict__ bk, short* __restrict__ WsrT) {
    const int bid = blockIdx.x, tid = threadIdx.x;
    __shared__ float t[64][65];
    if (bid < 2048) {
        const int y = bid & 63, ct = (bid >> 6) & 7, b = bid >> 9;
        {
            const int cc = tid >> 2, q = tid & 3;
            const float* xr = x + ((size_t)(b * C_ + ct * 64 + cc)) * N_ + y * 64;
            float s = 0.f;
#pragma unroll
            for (int jj = 0; jj < 4; ++jj) {
                float4 f = *reinterpret_cast<const float4*>(&xr[q * 16 + jj * 4]);
                int n = q * 16 + jj * 4;
                t[n + 0][cc] = f.x; t[n + 1][cc] = f.y;
                t[n + 2][cc] = f.z; t[n + 3][cc] = f.w;
                s += f.x + f.y + f.z + f.w;
            }
            s += __shfl_xor(s, 1);
            s += __shfl_xor(s, 2);
            if (q == 0) vpart[((size_t)(y * B_ + b)) * C_ + ct * 64 + cc] = s;
        }
        __syncthreads();
        {
            const int n = tid >> 2, c0 = (tid & 3) * 16;
            bf16x8 u0, u1;
#pragma unroll
            for (int j = 0; j < 8; ++j) {
                u0[j] = bf16s(t[n][c0 + j]);
                u1[j] = bf16s(t[n][c0 + 8 + j]);
            }
            short* dst = xT + ((size_t)(b * N_ + y * 64 + n)) * C_ + ct * 64 + c0;
            *reinterpret_cast<bf16x8*>(dst) = u0;
            *reinterpret_cast<bf16x8*>(dst + 8) = u1;
        }
    } else if (bid < 2560) {
        const int o = bid - 2048;
        float acc = 0.f;
        for (int c = tid; c < C_; c += 256) {
            float sc = rsqrtf(var[c] + EPS) * gamma[c];
            float wk = Wk[o * C_ + c];
            Wkp16[o * C_ + c] = bf16s(wk * sc);
            Wq16[o * C_ + c] = bf16s(Wq[o * C_ + c]);
            acc += wk * (sc * (bsr[c] - mean[c]) + beta[c]);
        }
        for (int m = 32; m; m >>= 1) acc += __shfl_xor(acc, m);
        if ((tid & 63) == 0) t[0][tid >> 6] = acc;
        __syncthreads();
        if (tid == 0) bk[o] = t[0][0] + t[0][1] + t[0][2] + t[0][3];
    } else {
        const int r = bid - 2560, kt = r & 31, ot = r >> 5;
        {
            const int cc = tid >> 2, q = tid & 3;
            const float* xr = Wsr + (size_t)(ot * 64 + cc) * 2048 + kt * 64;
#pragma unroll
            for (int jj = 0; jj < 4; ++jj) {
                float4 f = *reinterpret_cast<const float4*>(&xr[q * 16 + jj * 4]);
                int n = q * 16 + jj * 4;
                t[n + 0][cc] = f.x; t[n + 1][cc] = f.y;
                t[n + 2][cc] = f.z; t[n + 3][cc] = f.w;
            }
        }
        __syncthreads();
        {
            const int n = tid >> 2, c0 = (tid & 3) * 16;
            bf16x8 u0, u1;
#pragma unroll
            for (int j = 0; j < 8; ++j) {
                u0[j] = bf16s(t[n][c0 + j]);
                u1[j] = bf16s(t[n][c0 + 8 + j]);
            }
            int gkk = kt * 64 + n;                      // ci-major index
            int row2 = (gkk & 3) * 512 + (gkk >> 2);    // (dy,dx)-major index kk'
            short* dst = WsrT + (size_t)row2 * C_ + ot * 64 + c0;
            *reinterpret_cast<bf16x8*>(dst) = u0;
            *reinterpret_cast<bf16x8*>(dst + 8) = u1;
        }
    }
}

// ---------------------------------------------------------------------------
// m97-style GEMM core (128xBN tiles): acc += A[rows][K] * B[rows][K]^T
template <int MT>
__device__ __forceinline__ void gemm_core(const short* __restrict__ Ag,
                                          const short* __restrict__ Bg, int K,
                                          short* Abuf, short* Bbuf,
                                          f32x4 (&acc)[MT][4]) {
    const int tid = threadIdx.x;
    const int w = tid >> 6, l = tid & 63;
    const int lr = l & 15, lg = l >> 4;
    const int wm = w >> 1, wn = w & 1;
    const int srow = tid >> 3, scol = (tid & 7) * 8;
    char* AbufC = (char*)Abuf;
    char* BbufC = (char*)Bbuf;
    for (int kt = 0; kt < K; kt += 64) {
#pragma unroll
        for (int i = 0; i < MT; ++i)
            GLD16(Ag + (size_t)(i * 32 + srow) * K + kt + scol, AbufC + i * 4096 + tid * 16);
#pragma unroll
        for (int i = 0; i < 4; ++i)
            GLD16(Bg + (size_t)(i * 32 + srow) * K + kt + scol, BbufC + i * 4096 + tid * 16);
        __syncthreads();
        bf16x8 af[MT][2], bfv[4][2];
#pragma unroll
        for (int mt = 0; mt < MT; ++mt)
#pragma unroll
            for (int ks = 0; ks < 2; ++ks)
                af[mt][ks] = *reinterpret_cast<const bf16x8*>(
                    &Abuf[(wm * MT * 16 + mt * 16 + lr) * 64 + ks * 32 + lg * 8]);
#pragma unroll
        for (int nt = 0; nt < 4; ++nt)
#pragma unroll
            for (int ks = 0; ks < 2; ++ks)
                bfv[nt][ks] = *reinterpret_cast<const bf16x8*>(
                    &Bbuf[(wn * 64 + nt * 16 + lr) * 64 + ks * 32 + lg * 8]);
#pragma unroll
        for (int mt = 0; mt < MT; ++mt)
#pragma unroll
            for (int nt = 0; nt < 4; ++nt) {
                acc[mt][nt] = __builtin_amdgcn_mfma_f32_16x16x32_bf16(af[mt][0], bfv[nt][0], acc[mt][nt], 0, 0, 0);
                acc[mt][nt] = __builtin_amdgcn_mfma_f32_16x16x32_bf16(af[mt][1], bfv[nt][1], acc[mt][nt], 0, 0, 0);
            }
        __syncthreads();
    }
}

// ---------------------------------------------------------------------------
// P2 merged: Wck 64x64-tile GEMM (256 blocks) | pvred (32 blocks)
__global__ __launch_bounds__(256) void k_wckpv(const short* __restrict__ WsrT,
                                               const short* __restrict__ Wkp16,
                                               const float* __restrict__ vpart,
                                               const float* __restrict__ Wproj,
                                               short* __restrict__ Wck16,
                                               float* __restrict__ pv) {
    const int bid = blockIdx.x, tid = threadIdx.x;
    if (bid < 256) {
        __shared__ short Ab[64 * 64];
        __shared__ short Bb[64 * 64];
        const int m0 = (bid & 31) * 64;   // kk'
        const int n0 = (bid >> 5) * 64;   // o
        const int w = tid >> 6, l = tid & 63;
        const int lr = l & 15, lg = l >> 4, wm = w >> 1, wn = w & 1;
        const int srow = tid >> 3, scol = (tid & 7) * 8;  // shorts
        f32x4 acc[2][2];
#pragma unroll
        for (int i = 0; i < 2; ++i)
#pragma unroll
            for (int j = 0; j < 2; ++j) acc[i][j] = (f32x4){0.f, 0.f, 0.f, 0.f};
        char* AbC = (char*)Ab;
        char* BbC = (char*)Bb;
        for (int kt = 0; kt < 512; kt += 64) {
#pragma unroll
            for (int j = 0; j < 2; ++j) {
                GLD16(WsrT + (size_t)(m0 + j * 32 + srow) * 512 + kt + scol, AbC + j * 4096 + tid * 16);
                GLD16(Wkp16 + (size_t)(n0 + j * 32 + srow) * 512 + kt + scol, BbC + j * 4096 + tid * 16);
            }
            __syncthreads();
            bf16x8 af[2][2], bfv[2][2];
#pragma unroll
            for (int mt = 0; mt < 2; ++mt)
#pragma unroll
                for (int ks = 0; ks < 2; ++ks)
                    af[mt][ks] = *reinterpret_cast<const bf16x8*>(
                        &Ab[(wm * 32 + mt * 16 + lr) * 64 + ks * 32 + lg * 8]);
#pragma unroll
            for (int nt = 0; nt < 2; ++nt)
#pragma unroll
                for (int ks = 0; ks < 2; ++ks)
                    bfv[nt][ks] = *reinterpret_cast<const bf16x8*>(
                        &Bb[(wn * 32 + nt * 16 + lr) * 64 + ks * 32 + lg * 8]);
#pragma unroll
            for (int mt = 0; mt < 2; ++mt)
#pragma unroll
                for (int nt = 0; nt < 2; ++nt) {
                    acc[mt][nt] = __builtin_amdgcn_mfma_f32_16x16x32_bf16(af[mt][0], bfv[nt][0], acc[mt][nt], 0, 0, 0);
                    acc[mt][nt] = __builtin_amdgcn_mfma_f32_16x16x32_bf16(af[mt][1], bfv[nt][1], acc[mt][nt], 0, 0, 0);
                }
            __syncthreads();
        }
#pragma unroll
        for (int mt = 0; mt < 2; ++mt)
#pragma unroll
            for (int nt = 0; nt < 2; ++nt) {
                int kk0 = m0 + wm * 32 + mt * 16 + lg * 4;
                int o = n0 + wn * 32 + nt * 16 + lr;
                short4 u;
                u.x = bf16s(acc[mt][nt][0]);
                u.y = bf16s(acc[mt][nt][1]);
                u.z = bf16s(acc[mt][nt][2]);
                u.w = bf16s(acc[mt][nt][3]);
                *reinterpret_cast<short4*>(&Wck16[(size_t)o * 2048 + kk0]) = u;
            }
    } else {
        const int r = bid - 256, oc = r & 7, b = r >> 3;
        __shared__ float vs[512];
        float2 s = {0.f, 0.f};
        for (int y = 0; y < 64; ++y) {
            float2 f = *reinterpret_cast<const float2*>(&vpart[((size_t)(y * B_ + b)) * C_ + tid * 2]);
            s.x += f.x; s.y += f.y;
        }
        vs[tid * 2] = s.x * (1.f / N_);
        vs[tid * 2 + 1] = s.y * (1.f / N_);
        __syncthreads();
        const int w = tid >> 6, l = tid & 63;
#pragma unroll 4
        for (int i = 0; i < 16; ++i) {
            int o = oc * 64 + i * 4 + w;
            const float* wr = Wproj + (size_t)o * C_;
            float4 a = *reinterpret_cast<const float4*>(&wr[l * 8]);
            float4 b4 = *reinterpret_cast<const float4*>(&wr[l * 8 + 4]);
            float acc = a.x * vs[l * 8] + a.y * vs[l * 8 + 1] + a.z * vs[l * 8 + 2] + a.w * vs[l * 8 + 3] +
                        b4.x * vs[l * 8 + 4] + b4.y * vs[l * 8 + 5] + b4.z * vs[l * 8 + 6] + b4.w * vs[l * 8 + 7];
            for (int m = 32; m; m >>= 1) acc += __shfl_xor(acc, m);
            if (l == 0) pv[b * C_ + o] = acc;
        }
    }
}

// ---------------------------------------------------------------------------
// Fused q-GEMM + split-K(x4) k-GEMM. 1024 blocks, uniform K=512, XCD-swizzled.
__global__ __launch_bounds__(256) void k_gemm_qk2(const short* __restrict__ xT,
                                                  const short* __restrict__ Wq16,
                                                  const short* __restrict__ Wck16,
                                                  short* __restrict__ kp,
                                                  short* __restrict__ q2) {
    __shared__ short Abuf[128 * 64];
    __shared__ short Bbuf[128 * 64];
    f32x4 acc[4][4];
#pragma unroll
    for (int i = 0; i < 4; ++i)
#pragma unroll
        for (int j = 0; j < 4; ++j) acc[i][j] = (f32x4){0.f, 0.f, 0.f, 0.f};
    // XCD-aware swizzle (nwg=1024, 8 XCDs): each XCD gets a contiguous logical chunk
    const int bid = (blockIdx.x & 7) * 128 + (blockIdx.x >> 3);
    const int tid = threadIdx.x, l = tid & 63, w = tid >> 6;
    const int lr = l & 15, lg = l >> 4, wm = w >> 1, wn = w & 1;
    const int srow = tid >> 3, scol = (tid & 7) * 8;
    char* AbufC = (char*)Abuf;
    char* BbufC = (char*)Bbuf;

    if (bid < 512) {
        const int s = bid >> 7;            // dy*2 + dx
        const int dy = s >> 1, dx = s & 1;
        const int r2 = bid & 127;
        const int n0 = (r2 >> 2) * 128;    // act tile (bp)
        const int m0 = (r2 & 3) * 128;     // weight tile (o)
        for (int kt2 = 0; kt2 < 512; kt2 += 64) {
#pragma unroll
            for (int i = 0; i < 4; ++i) {
                int bp = n0 + i * 32 + srow;
                int b = bp >> 10, p = bp & 1023;
                int n = ((p >> 5) * 2 + dy) * 64 + (p & 31) * 2 + dx;
                GLD16(xT + ((size_t)(b * N_ + n)) * C_ + kt2 + scol, AbufC + i * 4096 + tid * 16);
            }
#pragma unroll
            for (int i = 0; i < 4; ++i)
                GLD16(Wck16 + (size_t)(m0 + i * 32 + srow) * 2048 + s * 512 + kt2 + scol,
                      BbufC + i * 4096 + tid * 16);
            __syncthreads();
            bf16x8 af[4][2], bfv[4][2];
#pragma unroll
            for (int mt = 0; mt < 4; ++mt)
#pragma unroll
                for (int ks = 0; ks < 2; ++ks)
                    af[mt][ks] = *reinterpret_cast<const bf16x8*>(
                        &Abuf[(wm * 64 + mt * 16 + lr) * 64 + ks * 32 + lg * 8]);
#pragma unroll
            for (int nt = 0; nt < 4; ++nt)
#pragma unroll
                for (int ks = 0; ks < 2; ++ks)
                    bfv[nt][ks] = *reinterpret_cast<const bf16x8*>(
                        &Bbuf[(wn * 64 + nt * 16 + lr) * 64 + ks * 32 + lg * 8]);
#pragma unroll
            for (int mt = 0; mt < 4; ++mt)
#pragma unroll
                for (int nt = 0; nt < 4; ++nt) {
                    acc[mt][nt] = __builtin_amdgcn_mfma_f32_16x16x32_bf16(af[mt][0], bfv[nt][0], acc[mt][nt], 0, 0, 0);
                    acc[mt][nt] = __builtin_amdgcn_mfma_f32_16x16x32_bf16(af[mt][1], bfv[nt][1], acc[mt][nt], 0, 0, 0);
                }
            __syncthreads();
        }
        short* kps = kp + (size_t)s * (4096 * 512);
#pragma unroll
        for (int mt = 0; mt < 4; ++mt)
#pragma unroll
            for (int nt = 0; nt < 4; ++nt) {
                int o = m0 + wn * 64 + nt * 16 + lr;
#pragma unroll
                for (int r = 0; r < 4; ++r) {
                    int bp = n0 + wm * 64 + mt * 16 + lg * 4 + r;
                    kps[(size_t)bp * 512 + o] = bf16s(acc[mt][nt][r]);
                }
            }
    } else {
        const int bq = bid - 512;
        const int m0 = (bq & 3) * 128, n0 = (bq >> 2) * 128;
        gemm_core<4>(Wq16 + (size_t)m0 * 512, xT + (size_t)n0 * 512, 512, Abuf, Bbuf, acc);
#pragma unroll
        for (int mt = 0; mt < 4; ++mt) {
            const int o0 = m0 + wm * 64 + mt * 16 + lg * 4;
            const int h = o0 >> 6, d0 = o0 & 63;
#pragma unroll
            for (int nt = 0; nt < 4; ++nt) {
                int ng = n0 + wn * 64 + nt * 16 + lr;
                int b = ng >> 12, n = ng & 4095;
                short4 u;
                u.x = bf16s(acc[mt][nt][0]);
                u.y = bf16s(acc[mt][nt][1]);
                u.z = bf16s(acc[mt][nt][2]);
                u.w = bf16s(acc[mt][nt][3]);
                *reinterpret_cast<short4*>(&q2[(((size_t)(b * NH_ + h)) * N_ + n) * HD_ + d0]) = u;
            }
        }
    }
}

// ---------------------------------------------------------------------------
// kred, 16B-vectorized: k3[b,h,p,d] = bf16( sum_s kp[s][bp][o] + bk[o] )
// grid 1024 x 256: each block 4 bp rows, each lane 8 o's.
__global__ __launch_bounds__(256) void k_kred(const short* __restrict__ kp,
                                              const float* __restrict__ bk,
                                              short* __restrict__ k3) {
    const int r = blockIdx.x * 4 + (threadIdx.x >> 6);   // bp row
    const int o0 = (threadIdx.x & 63) * 8;
    const int b = r >> 10, p = r & 1023;
    const short* base = kp + (size_t)r * 512 + o0;
    float s[8];
    float4 b0 = *reinterpret_cast<const float4*>(&bk[o0]);
    float4 b1 = *reinterpret_cast<const float4*>(&bk[o0 + 4]);
    s[0] = b0.x; s[1] = b0.y; s[2] = b0.z; s[3] = b0.w;
    s[4] = b1.x; s[5] = b1.y; s[6] = b1.z; s[7] = b1.w;
#pragma unroll
    for (int sp = 0; sp < 4; ++sp) {
        bf16x8 v = *reinterpret_cast<const bf16x8*>(base + (size_t)sp * (4096 * 512));
#pragma unroll
        for (int j = 0; j < 8; ++j) s[j] += bf2f(v[j]);
    }
    bf16x8 u;
#pragma unroll
    for (int j = 0; j < 8; ++j) u[j] = bf16s(s[j]);
    const int h = o0 >> 6, d = o0 & 63;
    *reinterpret_cast<bf16x8*>(&k3[(((size_t)(b * NH_ + h)) * NK + p) * HD_ + d]) = u;
}

// ---------------------------------------------------------------------------
// attention: am[b,h,n] = SCALE * max_p sum_d q[n,d]*k[p,d]
// A = k3 (rows p), B = q2 (cols n). Block: 256 n, 4 waves split 1024 p.
__global__ __launch_bounds__(256) void k_attn3(const short* __restrict__ k3,
                                               const short* __restrict__ q2,
                                               float* __restrict__ am) {
    const int b = blockIdx.z, h = blockIdx.y, n0 = blockIdx.x * 256;
    const int w = threadIdx.x >> 6, l = threadIdx.x & 63;
    const int lr = l & 15, lg = l >> 4;
    const short* qb = q2 + ((size_t)(b * NH_ + h)) * N_ * HD_;
    const short* kb = k3 + ((size_t)(b * NH_ + h)) * NK * HD_;

    bf16x8 bq[16][2];
#pragma unroll
    for (int nt = 0; nt < 16; ++nt)
#pragma unroll
        for (int ks = 0; ks < 2; ++ks)
            bq[nt][ks] = *reinterpret_cast<const bf16x8*>(
                &qb[(size_t)(n0 + nt * 16 + lr) * HD_ + ks * 32 + lg * 8]);

    float rmax[16];
#pragma unroll
    for (int nt = 0; nt < 16; ++nt) rmax[nt] = -3.4e38f;

    const short* kw = kb + (size_t)(w * 256) * HD_;
    const short* s0 = kw + (size_t)lr * HD_ + lg * 8;
    bf16x8 a0 = *reinterpret_cast<const bf16x8*>(s0);
    bf16x8 a1 = *reinterpret_cast<const bf16x8*>(s0 + 32);
    for (int t = 0; t < 16; ++t) {
        bf16x8 c0 = a0, c1 = a1;
        if (t < 15) {
            const short* s2 = kw + (size_t)((t + 1) * 16 + lr) * HD_ + lg * 8;
            a0 = *reinterpret_cast<const bf16x8*>(s2);
            a1 = *reinterpret_cast<const bf16x8*>(s2 + 32);
        }
        __builtin_amdgcn_s_setprio(1);
#pragma unroll
        for (int nt = 0; nt < 16; ++nt) {
            f32x4 acc = {0.f, 0.f, 0.f, 0.f};
            acc = __builtin_amdgcn_mfma_f32_16x16x32_bf16(c0, bq[nt][0], acc, 0, 0, 0);
            acc = __builtin_amdgcn_mfma_f32_16x16x32_bf16(c1, bq[nt][1], acc, 0, 0, 0);
            rmax[nt] = fmaxf(fmaxf(fmaxf(fmaxf(acc[0], acc[1]), acc[2]), acc[3]), rmax[nt]);
        }
        __builtin_amdgcn_s_setprio(0);
    }
#pragma unroll
    for (int nt = 0; nt < 16; ++nt) {
        float m = rmax[nt];
        m = fmaxf(m, __shfl_xor(m, 16));
        m = fmaxf(m, __shfl_xor(m, 32));
        rmax[nt] = m;
    }
    __shared__ float sm[4][256];
    if (lg == 0) {
#pragma unroll
        for (int nt = 0; nt < 16; ++nt) sm[w][nt * 16 + lr] = rmax[nt];
    }
    __syncthreads();
    {
        const int tid = threadIdx.x;
        float m = fmaxf(fmaxf(sm[0][tid], sm[1][tid]),
                        fmaxf(sm[2][tid], sm[3][tid]));
        am[((size_t)(b * NH_ + h)) * N_ + n0 + tid] = SCALE * m;
    }
}

// ---------------------------------------------------------------------------
// out[b,o,n] = pv[b,o] * (sum_h am[b,h,n]) + bproj[o]   (1024 blocks, 4/CU)
__global__ __launch_bounds__(256) void k_final(const float* __restrict__ pv, const float* __restrict__ am,
                                               const float* __restrict__ bproj, float* __restrict__ out) {
    const int b = blockIdx.z, o0 = blockIdx.y * 64 + (threadIdx.x >> 5) * 8;
    const int n = blockIdx.x * 128 + (threadIdx.x & 31) * 4;
    float4 s = {0.f, 0.f, 0.f, 0.f};
#pragma unroll
    for (int h = 0; h < NH_; ++h) {
        float4 a = *reinterpret_cast<const float4*>(&am[((size_t)(b * NH_ + h)) * N_ + n]);
        s.x += a.x; s.y += a.y; s.z += a.z; s.w += a.w;
    }
    float* ob = out + (size_t)b * C_ * N_ + n;
    const float* pvb = pv + b * C_;
#pragma unroll
    for (int i = 0; i < 8; ++i) {
        int o = o0 + i;
        float p = pvb[o], bp = bproj[o];
        float4 r = {p * s.x + bp, p * s.y + bp, p * s.z + bp, p * s.w + bp};
        *reinterpret_cast<float4*>(&ob[(size_t)o * N_]) = r;
    }
}

// ---------------------------------------------------------------------------
extern "C" void kernel_launch(void* const* d_in, const int* in_sizes, int n_in,
                              void* d_out, int out_size, void* d_ws, size_t ws_size,
                              hipStream_t stream) {
    const float* x     = (const float*)d_in[0];
    const float* Wq    = (const float*)d_in[2];
    const float* Wk    = (const float*)d_in[3];
    const float* Wsr   = (const float*)d_in[4];
    const float* bsr   = (const float*)d_in[5];
    const float* gamma = (const float*)d_in[6];
    const float* beta  = (const float*)d_in[7];
    const float* mean  = (const float*)d_in[8];
    const float* var   = (const float*)d_in[9];
    const float* Wproj = (const float*)d_in[10];
    const float* bproj = (const float*)d_in[11];
    float* out = (float*)d_out;

    char* ws = (char*)d_ws;
    float* vpart = (float*)(ws + 0);         // 512 KB [64][B][C]
    float* pv    = (float*)(ws + 524288);    // 8 KB
    float* bk    = (float*)(ws + 532480);    // 4 KB
    float* am    = (float*)(ws + 536576);    // 512 KB
    short* Wq16  = (short*)(ws + 1060864);   // 512 KB
    short* Wkp16 = (short*)(ws + 1585152);   // 512 KB
    short* WsrT  = (short*)(ws + 2109440);   // 2 MB   [kk'][co] bf16
    short* Wck16 = (short*)(ws + 4206592);   // 2 MB   [o][kk'] bf16
    short* xT    = (short*)(ws + 6303744);   // 16 MB  [b,n,c] bf16
    short* q2    = (short*)(ws + 23080960);  // 16 MB  [b,h,n,d] bf16
    short* k3    = (short*)(ws + 39858176);  // 4 MB   [b,h,p,d] bf16
    short* kp    = (short*)(ws + 44052480);  // 16 MB  [4][4096][512] bf16

    k_xw<<<dim3(2816), 256, 0, stream>>>(x, Wq, Wk, gamma, beta, mean, var, bsr, Wsr,
                                         xT, vpart, Wq16, Wkp16, bk, WsrT);
    k_wckpv<<<dim3(288), 256, 0, stream>>>(WsrT, Wkp16, vpart, Wproj, Wck16, pv);
    k_gemm_qk2<<<dim3(1024), 256, 0, stream>>>(xT, Wq16, Wck16, kp, q2);
    k_kred<<<dim3(1024), 256, 0, stream>>>(kp, bk, k3);
    k_attn3<<<dim3(16, NH_, B_), 256, 0, stream>>>(k3, q2, am);
    k_final<<<dim3(32, 8, B_), 256, 0, stream>>>(pv, am, bproj, out);
}